// Round 6
// baseline (6980.462 us; speedup 1.0000x reference)
//
#include <hip/hip_runtime.h>
#include <stdint.h>

// ---------------- problem constants ----------------
#define S_LEN 512
#define B_SZ  64
#define E_DIM 512
#define HD    1024
#define NGATE 3072   // 3*HD (r,z,c)
#define O_DIM 10

typedef __attribute__((ext_vector_type(4))) float f32x4;
typedef __attribute__((ext_vector_type(8))) short bf16x8;   // 8 bf16 in 4 VGPRs

__device__ __forceinline__ float bf2f(unsigned short u) {
  union { unsigned int i; float f; } c; c.i = ((unsigned int)u) << 16; return c.f;
}
__device__ __forceinline__ unsigned short f2bf(float f) {   // RNE
  union { float f; unsigned int i; } c; c.f = f;
  unsigned int u = c.i;
  return (unsigned short)((u + 0x7fffu + ((u >> 16) & 1u)) >> 16);
}
__device__ __forceinline__ float sigmoid_fast(float x) { return 1.0f / (1.0f + __expf(-x)); }
__device__ __forceinline__ float tanh_fast(float x) {
  float a = fabsf(x);
  float e = __expf(2.0f * a);
  return copysignf(1.0f - 2.0f / (e + 1.0f), x);
}
__device__ __forceinline__ f32x4 mfma16(bf16x8 a, bf16x8 b, f32x4 c) {
  return __builtin_amdgcn_mfma_f32_16x16x32_bf16(a, b, c, 0, 0, 0);
}
// ---- device-coherent primitives (relaxed agent scope) ----
__device__ __forceinline__ unsigned long long ld_u64_agent(const unsigned long long* p) {
  return __hip_atomic_load(p, __ATOMIC_RELAXED, __HIP_MEMORY_SCOPE_AGENT);
}
__device__ __forceinline__ void st_u64_agent(unsigned long long* p, unsigned long long v) {
  __hip_atomic_store(p, v, __ATOMIC_RELAXED, __HIP_MEMORY_SCOPE_AGENT);
}

// red[] index swizzle: XOR bits5-6 into bits3-4. Breaks the 4-way bank
// conflict of the scalar reduce-reads while preserving 16B alignment of the
// f32x4 accesses (bits0-1 untouched). Bijective within [0,256).
__device__ __forceinline__ int ridx(int i) { return i ^ (((i >> 5) & 3) << 3); }

// ---------------- ws layout (bytes) ----------------
// R9: SELF-TAGGED u64 exchange, flags deleted.  Every exchanged u64 =
// (seq32<<32)|(2x bf16).  Aligned 8B stores/loads are single-copy atomic ->
// tag and data cannot tear.  Producer: ONE fire-and-forget store (no vmcnt
// drain, no flag).  Consumer: early-issued bulk loads + retry-only-stale
// validate (per-lane predication) -- unlike R5, retries do NOT re-sweep the
// full payload, and the first pass is latency-hidden under z-MFMA / tail.
// Chunk = [16 rows][16 u64] = 2 KB per (group,block).
#define OFF_HB2   0          // u64 Hb2[2][4][32][256] tagged = 512 KB
#define OFF_RH2   524288     // u64 rh2[4][32][256] tagged    = 256 KB
#define OFF_HF    786432     // f32 Hf[64][1024]              = 256 KB
#define OFF_ZSCR  786432     // memset end (Hb2 + rh2; tag0 == valid H0)
#define OFF_WR    1704960
#define OFF_WZ    3802112
#define OFF_WC    5899264
#define OFF_WX    7996416
#define OFF_XP    11142144

// ============================================================================
// convert: fp32 weights -> bf16, pre-swizzled into MFMA B-fragment order.
// ============================================================================
__global__ void convert_kernel(const float* __restrict__ Whr, const float* __restrict__ Whz,
                               const float* __restrict__ Whc,
                               const float* __restrict__ Wxr, const float* __restrict__ Wxz,
                               const float* __restrict__ Wxc,
                               unsigned short* __restrict__ Wr_swz, unsigned short* __restrict__ Wz_swz,
                               unsigned short* __restrict__ Wc_swz, unsigned short* __restrict__ Wx_swz) {
  long idx = (long)blockIdx.x * blockDim.x + threadIdx.x;
  const long NH = (long)HD * HD;
  if (idx < 3 * NH) {
    int m = (int)(idx >> 20);
    int t = (int)(idx & (NH - 1));
    int k = t >> 10, j = t & 1023;
    const float* src = (m == 0) ? Whr : (m == 1) ? Whz : Whc;
    unsigned short* dst = (m == 0) ? Wr_swz : (m == 1) ? Wz_swz : Wc_swz;
    int jt = j >> 4, n = j & 15, kt = k >> 5, q = (k >> 3) & 3, i = k & 7;
    dst[((long)(jt * 32 + kt) * 64 + (q * 16 + n)) * 8 + i] = f2bf(src[(long)k * HD + j]);
  } else {
    long t = idx - 3 * NH;
    if (t < (long)E_DIM * NGATE) {
      int e  = (int)(t / NGATE);
      int jg = (int)(t - (long)e * NGATE);
      int jt = jg >> 4, n = jg & 15, kt = e >> 5, q = (e >> 3) & 3, i = e & 7;
      int gate = jg >> 10, jj = jg & 1023;
      const float* src = (gate == 0) ? Wxr : (gate == 1) ? Wxz : Wxc;
      Wx_swz[((long)(jt * 16 + kt) * 64 + (q * 16 + n)) * 8 + i] = f2bf(src[(long)e * HD + jj]);
    }
  }
}

// ============================================================================
// embed + X-projection -> Xp[s][g][jglob][16b] (bf16, bias folded in).
// ============================================================================
__launch_bounds__(256, 2)
__global__ void embed_kernel(const int* __restrict__ tokens,
                             const float* __restrict__ Emb,
                             const unsigned short* __restrict__ Wx_swz,
                             const float* __restrict__ b_r, const float* __restrict__ b_z,
                             const float* __restrict__ b_c,
                             unsigned short* __restrict__ Xp) {
  __shared__ unsigned short xl[B_SZ * E_DIM];   // 64 KB
  const int s = blockIdx.y;
  const int slab = blockIdx.x;                  // 0..47
  const int tid = threadIdx.x;
  for (int it = 0; it < 32; ++it) {
    int task = tid + 256 * it;
    int row = task >> 7;
    int f = task & 127;
    int tok = tokens[row * S_LEN + s];
    float4 v = *(const float4*)(Emb + (long)tok * E_DIM + f * 4);
    int sw = (f >> 1) ^ (row & 7);
    unsigned short* p = xl + row * E_DIM + sw * 8 + (f & 1) * 4;
    p[0] = f2bf(v.x); p[1] = f2bf(v.y); p[2] = f2bf(v.z); p[3] = f2bf(v.w);
  }
  __syncthreads();
  const int lane = tid & 63, wave = tid >> 6;
  const int n = lane & 15, q = lane >> 4;
  const int jt_glob = slab * 4 + wave;
  f32x4 acc[4];
  #pragma unroll
  for (int bt = 0; bt < 4; ++bt) { acc[bt][0]=0.f; acc[bt][1]=0.f; acc[bt][2]=0.f; acc[bt][3]=0.f; }
  for (int kt = 0; kt < 16; ++kt) {
    bf16x8 bfrag = *(const bf16x8*)(Wx_swz + ((long)(jt_glob * 16 + kt) * 64 + lane) * 8);
    #pragma unroll
    for (int bt = 0; bt < 4; ++bt) {
      int row = bt * 16 + n;
      int chunk = (kt * 4 + q) ^ (row & 7);
      bf16x8 afrag = *(const bf16x8*)(xl + row * E_DIM + chunk * 8);
      acc[bt] = mfma16(afrag, bfrag, acc[bt]);
    }
  }
  const int jglob = jt_glob * 16 + n;
  const int gate = jglob >> 10, jj = jglob & 1023;
  const float bias = (gate == 0 ? b_r : gate == 1 ? b_z : b_c)[jj];
  #pragma unroll
  for (int bt = 0; bt < 4; ++bt) {              // bt == batch group
    unsigned int lo = (unsigned)f2bf(acc[bt][0] + bias) | ((unsigned)f2bf(acc[bt][1] + bias) << 16);
    unsigned int hi = (unsigned)f2bf(acc[bt][2] + bias) | ((unsigned)f2bf(acc[bt][3] + bias) << 16);
    uint2 pk; pk.x = lo; pk.y = hi;             // rows 4q..4q+3 within group
    *(uint2*)(Xp + (((long)s * 4 + bt) * NGATE + jglob) * 16 + q * 4) = pk;
  }
}

// ============================================================================
// persistent GRU (R9): self-tagged u64 exchange, zero flags, zero drains.
// Per step (3 barriers):
//   validate-H (retry-only-stale) -> r-MFMA -> bar1 -> produce-rh (1 store)
//   -> issue rh first-pass loads -> z-MFMA -> validate-rh -> bar2
//   -> z-reduce (w2,3) -> c-MFMA -> bar3 -> produce-H (1 store)
//   -> tail: Xp prefetch + issue H first-pass loads
// H per-lane state (h0r,h1r) lives in REGISTERS (produce maps are identical).
// red/zbuf accesses XOR-swizzled (ridx) -> 4-way bank conflicts removed.
// ============================================================================
__launch_bounds__(256, 1)
__global__ void gru_kernel(const unsigned short* __restrict__ Xp,
                           const unsigned short* __restrict__ Wr_swz,
                           const unsigned short* __restrict__ Wz_swz,
                           const unsigned short* __restrict__ Wc_swz,
                           unsigned long long* __restrict__ Hb2,  // [2][4][32][256] tagged
                           float* __restrict__ Hf,                // [64][1024] f32 (last step)
                           unsigned long long* __restrict__ rh2) {// [4][32][256] tagged
  __shared__ float red[4][6][256];              // 24 KB [src wave][slot][...]
  __shared__ float zbuf[16 * 33];               // 2.1 KB padded [row][col]

  const int tid = threadIdx.x;
  const int lane = tid & 63, w = tid >> 6;
  const int n = lane & 15, q = lane >> 4;
  const int blk = blockIdx.x;                   // 0..127
  const int g  = blk & 3;                       // batch group (rows 16g..16g+15)
  const int bh = blk >> 2;                      // j-slice [32bh, 32bh+32), bh 0..31

  // produce mapping: wave w -> rows [4w,4w+4); lane -> (row 4w+rr, cols pc,pc+1)
  const int rr = lane >> 4;                     // 0..3
  const int m  = lane & 15;
  const int prow = 4 * w + rr;                  // 0..15
  const int pc = 2 * m;                         // 0..30 (even)
  const int t0 = pc >> 4;                       // tile (same for pc, pc+1)
  const int n0 = pc & 15;

  // swizzled LDS indices (precomputed)
  const int sidx  = ridx(lane * 4);                          // vector slot
  const int pidx0 = ridx((w * 16 + n0) * 4 + rr);            // produce read, col pc
  const int pidx1 = ridx((w * 16 + n0 + 1) * 4 + rr);        // produce read, col pc+1

  // ---- weights -> registers: per-wave K-quarter (kt = w*8..w*8+7), 2 j-tiles ----
  bf16x8 wr_reg[2][8], wz_reg[2][8], wc_reg[2][8];
  #pragma unroll
  for (int jt = 0; jt < 2; ++jt)
    #pragma unroll
    for (int t = 0; t < 8; ++t) {
      long o = ((long)((2 * bh + jt) * 32 + w * 8 + t)) * 512 + lane * 8;
      wr_reg[jt][t] = *(const bf16x8*)(Wr_swz + o);
      wz_reg[jt][t] = *(const bf16x8*)(Wz_swz + o);
      wc_reg[jt][t] = *(const bf16x8*)(Wc_swz + o);
    }

  // per-lane H state (registers; produce-rh and produce-H use the same map)
  float h0r = 0.f, h1r = 0.f;                   // H0 = 0

  // Xp addresses (layout: [s][g][jglob][row0..15])
  const long xp_step = (long)4 * NGATE * 16;    // shorts per step
  const unsigned short* xr_p = Xp + ((long)g * NGATE + bh * 32 + pc) * 16 + prow;
  const unsigned short* xc_p = Xp + ((long)g * NGATE + 2 * HD + bh * 32 + pc) * 16 + prow;
  const unsigned short* xz_p = Xp + ((long)g * NGATE + HD + bh * 32 + (w & 1) * 16 + n) * 16 + q * 4;

  unsigned short xr0 = xr_p[0],  xr1 = xr_p[16];
  unsigned short xc0 = xc_p[0],  xc1 = xc_p[16];
  uint2 xz; xz.x = 0; xz.y = 0;
  if (w >= 2) xz = *(const uint2*)xz_p;

  // producer store offset (u64 units): chunk (g,bh), row prow, col-pair m
  const long my64 = (long)(g * 32 + bh) * 256 + (long)prow * 16 + m;
  // consumer element base within a chunk: row n, col-pairs q*4..q*4+4
  const long celem = (long)n * 16 + q * 4;
  const long cbase = (long)(g * 32 + w * 8) * 256 + celem;   // chunk t adds t*256

  // ---- first-pass H loads (buf 0; tag 0 == valid H0 via memset) ----
  unsigned long long a_[8][4];
  {
    const unsigned long long* hb = Hb2 + cbase;
    #pragma unroll
    for (int t = 0; t < 8; ++t)
      #pragma unroll
      for (int j = 0; j < 4; ++j) a_[t][j] = ld_u64_agent(hb + t * 256 + j);
  }

  int cur = 0;
  for (int s = 0; s < S_LEN; ++s) {
    const unsigned int expH = 2u * (unsigned int)s;
    const unsigned int tagR = expH + 1u;
    const unsigned int tagH = expH + 2u;

    // ---- validate H (retry only stale elements) ----
    {
      const unsigned long long* hb = Hb2 + (long)cur * 32768 + cbase;
      for (;;) {
        int nbad = 0;
        #pragma unroll
        for (int t = 0; t < 8; ++t)
          #pragma unroll
          for (int j = 0; j < 4; ++j)
            if ((unsigned int)(a_[t][j] >> 32) < expH) {
              a_[t][j] = ld_u64_agent(hb + t * 256 + j);
              nbad = 1;
            }
        if (!nbad) break;
      }
    }

    // ---- r-MFMA ----
    f32x4 aR0, aR1;
    aR0[0]=0.f;aR0[1]=0.f;aR0[2]=0.f;aR0[3]=0.f; aR1 = aR0;
    #pragma unroll
    for (int t = 0; t < 8; ++t) {
      union { unsigned int u[4]; bf16x8 v; } af;
      #pragma unroll
      for (int j = 0; j < 4; ++j) af.u[j] = (unsigned int)a_[t][j];
      aR0 = mfma16(af.v, wr_reg[0][t], aR0);
      aR1 = mfma16(af.v, wr_reg[1][t], aR1);
    }
    *(f32x4*)&red[w][0][sidx] = aR0;
    *(f32x4*)&red[w][1][sidx] = aR1;
    __syncthreads();                              // bar1
    // ---- produce rh: ONE tagged store, fire-and-forget ----
    {
      float v0 = 0.f, v1 = 0.f;
      #pragma unroll
      for (int k = 0; k < 4; ++k) {
        v0 += red[k][t0][pidx0];
        v1 += red[k][t0][pidx1];
      }
      float r0 = sigmoid_fast(v0 + bf2f(xr0)) * h0r;
      float r1 = sigmoid_fast(v1 + bf2f(xr1)) * h1r;
      unsigned int pay = (unsigned)f2bf(r0) | ((unsigned)f2bf(r1) << 16);
      st_u64_agent(rh2 + my64, ((unsigned long long)tagR << 32) | pay);
    }
    // ---- first-pass rh loads (fly during z-MFMA) ----
    unsigned long long r_[8][4];
    {
      const unsigned long long* rb = rh2 + cbase;
      #pragma unroll
      for (int t = 0; t < 8; ++t)
        #pragma unroll
        for (int j = 0; j < 4; ++j) r_[t][j] = ld_u64_agent(rb + t * 256 + j);
    }
    // ---- z-MFMA ----
    f32x4 aZ0, aZ1;
    aZ0[0]=0.f;aZ0[1]=0.f;aZ0[2]=0.f;aZ0[3]=0.f; aZ1 = aZ0;
    #pragma unroll
    for (int t = 0; t < 8; ++t) {
      union { unsigned int u[4]; bf16x8 v; } af;
      #pragma unroll
      for (int j = 0; j < 4; ++j) af.u[j] = (unsigned int)a_[t][j];
      aZ0 = mfma16(af.v, wz_reg[0][t], aZ0);
      aZ1 = mfma16(af.v, wz_reg[1][t], aZ1);
    }
    *(f32x4*)&red[w][2][sidx] = aZ0;
    *(f32x4*)&red[w][3][sidx] = aZ1;
    // ---- validate rh ----
    {
      const unsigned long long* rb = rh2 + cbase;
      for (;;) {
        int nbad = 0;
        #pragma unroll
        for (int t = 0; t < 8; ++t)
          #pragma unroll
          for (int j = 0; j < 4; ++j)
            if ((unsigned int)(r_[t][j] >> 32) < tagR) {
              r_[t][j] = ld_u64_agent(rb + t * 256 + j);
              nbad = 1;
            }
        if (!nbad) break;
      }
    }
    __syncthreads();                              // bar2 (z partials visible)
    if (w >= 2) {                                 // z-reduce, tile tz = w-2
      const int tz = w - 2;
      f32x4 accz = *(const f32x4*)&red[0][2 + tz][sidx];
      #pragma unroll
      for (int k = 1; k < 4; ++k) { f32x4 p = *(const f32x4*)&red[k][2 + tz][sidx]; accz += p; }
      #pragma unroll
      for (int r_i = 0; r_i < 4; ++r_i) {
        float xpv = bf2f((unsigned short)(((r_i < 2) ? xz.x : xz.y) >> ((r_i & 1) * 16)));
        zbuf[(q * 4 + r_i) * 33 + tz * 16 + n] = sigmoid_fast(accz[r_i] + xpv);
      }
    }
    // ---- c-MFMA ----
    f32x4 cA, cB;
    cA[0]=0.f;cA[1]=0.f;cA[2]=0.f;cA[3]=0.f; cB = cA;
    #pragma unroll
    for (int t = 0; t < 8; ++t) {
      union { unsigned int u[4]; bf16x8 v; } af;
      #pragma unroll
      for (int j = 0; j < 4; ++j) af.u[j] = (unsigned int)r_[t][j];
      cA = mfma16(af.v, wc_reg[0][t], cA);
      cB = mfma16(af.v, wc_reg[1][t], cB);
    }
    *(f32x4*)&red[w][4][sidx] = cA;
    *(f32x4*)&red[w][5][sidx] = cB;
    __syncthreads();                              // bar3
    // ---- produce H: ONE tagged store, fire-and-forget ----
    {
      float v0 = 0.f, v1 = 0.f;
      #pragma unroll
      for (int k = 0; k < 4; ++k) {
        v0 += red[k][4 + t0][pidx0];
        v1 += red[k][4 + t0][pidx1];
      }
      float cv0 = tanh_fast(v0 + bf2f(xc0));
      float cv1 = tanh_fast(v1 + bf2f(xc1));
      float z0 = zbuf[prow * 33 + pc], z1 = zbuf[prow * 33 + pc + 1];
      float hn0 = z0 * h0r + (1.0f - z0) * cv0;
      float hn1 = z1 * h1r + (1.0f - z1) * cv1;
      h0r = hn0; h1r = hn1;
      if (s == S_LEN - 1) {
        Hf[(long)(g * 16 + prow) * HD + bh * 32 + pc]     = hn0;
        Hf[(long)(g * 16 + prow) * HD + bh * 32 + pc + 1] = hn1;
      }
      unsigned int pay = (unsigned)f2bf(hn0) | ((unsigned)f2bf(hn1) << 16);
      st_u64_agent(Hb2 + (long)(cur ^ 1) * 32768 + my64,
                   ((unsigned long long)tagH << 32) | pay);
    }
    // ---- tail: Xp prefetch + first-pass H loads for next step ----
    if (s < S_LEN - 1) {
      const unsigned short* xr_s = xr_p + (long)(s + 1) * xp_step;
      const unsigned short* xc_s = xc_p + (long)(s + 1) * xp_step;
      unsigned short xr0n = xr_s[0], xr1n = xr_s[16];
      unsigned short xc0n = xc_s[0], xc1n = xc_s[16];
      uint2 xzn; xzn.x = 0; xzn.y = 0;
      if (w >= 2) xzn = *(const uint2*)(xz_p + (long)(s + 1) * xp_step);
      const unsigned long long* hb = Hb2 + (long)(cur ^ 1) * 32768 + cbase;
      #pragma unroll
      for (int t = 0; t < 8; ++t)
        #pragma unroll
        for (int j = 0; j < 4; ++j) a_[t][j] = ld_u64_agent(hb + t * 256 + j);
      xr0 = xr0n; xr1 = xr1n; xc0 = xc0n; xc1 = xc1n; xz = xzn;
    }
    cur ^= 1;
  }
}

// ============================================================================
// logits + softmax: one wave per batch row
// ============================================================================
__global__ void logits_kernel(const float* __restrict__ Hf, const float* __restrict__ Whq,
                              const float* __restrict__ bq, float* __restrict__ out) {
  const int b = blockIdx.x;
  const int lane = threadIdx.x;   // 64
  float acc[O_DIM];
  #pragma unroll
  for (int o = 0; o < O_DIM; ++o) acc[o] = 0.f;
  for (int k = lane; k < HD; k += 64) {
    float h = Hf[(long)b * HD + k];
    #pragma unroll
    for (int o = 0; o < O_DIM; ++o) acc[o] += h * Whq[(long)k * O_DIM + o];
  }
  #pragma unroll
  for (int o = 0; o < O_DIM; ++o) {
    #pragma unroll
    for (int off = 32; off > 0; off >>= 1) acc[o] += __shfl_down(acc[o], off, 64);
  }
  if (lane == 0) {
    float lg[O_DIM], m = -1e30f, sum = 0.f;
    #pragma unroll
    for (int o = 0; o < O_DIM; ++o) { lg[o] = acc[o] + bq[o]; m = fmaxf(m, lg[o]); }
    #pragma unroll
    for (int o = 0; o < O_DIM; ++o) { lg[o] = __expf(lg[o] - m); sum += lg[o]; }
    float inv = 1.0f / sum;
    #pragma unroll
    for (int o = 0; o < O_DIM; ++o) out[(long)b * O_DIM + o] = lg[o] * inv;
  }
}

// ============================================================================
extern "C" void kernel_launch(void* const* d_in, const int* in_sizes, int n_in,
                              void* d_out, int out_size, void* d_ws, size_t ws_size,
                              hipStream_t stream) {
  const int*   tokens = (const int*)d_in[0];
  const float* Emb = (const float*)d_in[1];
  const float* Wxr = (const float*)d_in[2];
  const float* Whr = (const float*)d_in[3];
  const float* br  = (const float*)d_in[4];
  const float* Wxz = (const float*)d_in[5];
  const float* Whz = (const float*)d_in[6];
  const float* bz  = (const float*)d_in[7];
  const float* Wxc = (const float*)d_in[8];
  const float* Whc = (const float*)d_in[9];
  const float* bc  = (const float*)d_in[10];
  const float* Whq = (const float*)d_in[11];
  const float* bq  = (const float*)d_in[12];

  char* ws = (char*)d_ws;
  unsigned long long* Hb2 = (unsigned long long*)(ws + OFF_HB2);
  unsigned long long* rh2 = (unsigned long long*)(ws + OFF_RH2);
  float*          Hf     = (float*)(ws + OFF_HF);
  unsigned short* Wr_swz = (unsigned short*)(ws + OFF_WR);
  unsigned short* Wz_swz = (unsigned short*)(ws + OFF_WZ);
  unsigned short* Wc_swz = (unsigned short*)(ws + OFF_WC);
  unsigned short* Wx_swz = (unsigned short*)(ws + OFF_WX);
  unsigned short* Xp     = (unsigned short*)(ws + OFF_XP);

  // zero tagged buffers: tag0+data0 == valid H0; rh tags start stale
  hipMemsetAsync(ws, 0, OFF_ZSCR, stream);

  convert_kernel<<<18432, 256, 0, stream>>>(Whr, Whz, Whc, Wxr, Wxz, Wxc,
                                            Wr_swz, Wz_swz, Wc_swz, Wx_swz);
  embed_kernel<<<dim3(48, S_LEN), 256, 0, stream>>>(tokens, Emb, Wx_swz, br, bz, bc, Xp);
  gru_kernel<<<128, 256, 0, stream>>>(Xp, Wr_swz, Wz_swz, Wc_swz, Hb2, Hf, rh2);
  logits_kernel<<<B_SZ, 64, 0, stream>>>(Hf, Whq, bq, (float*)d_out);
}

// Round 7
// 3409.939 us; speedup vs baseline: 2.0471x; 2.0471x over previous
//
#include <hip/hip_runtime.h>
#include <stdint.h>

// ---------------- problem constants ----------------
#define S_LEN 512
#define B_SZ  64
#define E_DIM 512
#define HD    1024
#define NGATE 3072   // 3*HD (r,z,c)
#define O_DIM 10

typedef __attribute__((ext_vector_type(4))) float f32x4;
typedef __attribute__((ext_vector_type(8))) short bf16x8;   // 8 bf16 in 4 VGPRs

__device__ __forceinline__ float bf2f(unsigned short u) {
  union { unsigned int i; float f; } c; c.i = ((unsigned int)u) << 16; return c.f;
}
__device__ __forceinline__ unsigned short f2bf(float f) {   // RNE
  union { float f; unsigned int i; } c; c.f = f;
  unsigned int u = c.i;
  return (unsigned short)((u + 0x7fffu + ((u >> 16) & 1u)) >> 16);
}
__device__ __forceinline__ float sigmoid_fast(float x) { return 1.0f / (1.0f + __expf(-x)); }
__device__ __forceinline__ float tanh_fast(float x) {
  float a = fabsf(x);
  float e = __expf(2.0f * a);
  return copysignf(1.0f - 2.0f / (e + 1.0f), x);
}
__device__ __forceinline__ f32x4 mfma16(bf16x8 a, bf16x8 b, f32x4 c) {
  return __builtin_amdgcn_mfma_f32_16x16x32_bf16(a, b, c, 0, 0, 0);
}
// ---- device-coherent primitives (relaxed agent scope, R6/R8-proven) ----
__device__ __forceinline__ unsigned long long ld_u64_agent(const unsigned long long* p) {
  return __hip_atomic_load(p, __ATOMIC_RELAXED, __HIP_MEMORY_SCOPE_AGENT);
}
__device__ __forceinline__ unsigned int ld_u32_agent(const unsigned int* p) {
  return __hip_atomic_load(p, __ATOMIC_RELAXED, __HIP_MEMORY_SCOPE_AGENT);
}
__device__ __forceinline__ void st_u32_agent(unsigned int* p, unsigned int v) {
  __hip_atomic_store(p, v, __ATOMIC_RELAXED, __HIP_MEMORY_SCOPE_AGENT);
}

// red[] index swizzle: XOR bits5-7 into bits2-4.  Bijective on [0,256);
// keeps f32x4 accesses 16B-contiguous (bits0-1 untouched; 4-aligned blocks
// never straddle a bit-5 boundary).  Produce-path scalar reads go from
// 4-way bank conflict to 2-way (free, m136); vector writes keep the same
// bank multiset as unswizzled.
__device__ __forceinline__ int swz(int i) { return i ^ (((i >> 5) & 7) << 2); }

// ---------------- ws layout (bytes) ----------------
// R10 == R8 protocol (flags + bulk payload; proven 2763 us) with the
// produce-path de-conflicted.  Payload chunks: [16 rows][32 cols] bf16 = 1KB.
#define SLOT_STRIDE 64       // u32s per flag slot = 256 B
#define OFF_HB2   0          // bf16 Hb2[2][4][32][16][32] = 256 KB
#define OFF_RH2   262144     // bf16 rh2[4][32][16][32]   = 128 KB
#define OFF_HF    393216     // f32 Hf[64][1024]          = 256 KB
#define OFF_SLOTS 655360     // u32 [4][32][4] x 256 B    = 128 KB
#define OFF_WR    1704960
#define OFF_WZ    3802112
#define OFF_WC    5899264
#define OFF_WX    7996416
#define OFF_XP    11142144

// ============================================================================
// convert: fp32 weights -> bf16, pre-swizzled into MFMA B-fragment order.
// ============================================================================
__global__ void convert_kernel(const float* __restrict__ Whr, const float* __restrict__ Whz,
                               const float* __restrict__ Whc,
                               const float* __restrict__ Wxr, const float* __restrict__ Wxz,
                               const float* __restrict__ Wxc,
                               unsigned short* __restrict__ Wr_swz, unsigned short* __restrict__ Wz_swz,
                               unsigned short* __restrict__ Wc_swz, unsigned short* __restrict__ Wx_swz) {
  long idx = (long)blockIdx.x * blockDim.x + threadIdx.x;
  const long NH = (long)HD * HD;
  if (idx < 3 * NH) {
    int m = (int)(idx >> 20);
    int t = (int)(idx & (NH - 1));
    int k = t >> 10, j = t & 1023;
    const float* src = (m == 0) ? Whr : (m == 1) ? Whz : Whc;
    unsigned short* dst = (m == 0) ? Wr_swz : (m == 1) ? Wz_swz : Wc_swz;
    int jt = j >> 4, n = j & 15, kt = k >> 5, q = (k >> 3) & 3, i = k & 7;
    dst[((long)(jt * 32 + kt) * 64 + (q * 16 + n)) * 8 + i] = f2bf(src[(long)k * HD + j]);
  } else {
    long t = idx - 3 * NH;
    if (t < (long)E_DIM * NGATE) {
      int e  = (int)(t / NGATE);
      int jg = (int)(t - (long)e * NGATE);
      int jt = jg >> 4, n = jg & 15, kt = e >> 5, q = (e >> 3) & 3, i = e & 7;
      int gate = jg >> 10, jj = jg & 1023;
      const float* src = (gate == 0) ? Wxr : (gate == 1) ? Wxz : Wxc;
      Wx_swz[((long)(jt * 16 + kt) * 64 + (q * 16 + n)) * 8 + i] = f2bf(src[(long)e * HD + jj]);
    }
  }
}

// ============================================================================
// embed + X-projection -> Xp[s][g][jglob][16b] (bf16, bias folded in).
// ============================================================================
__launch_bounds__(256, 2)
__global__ void embed_kernel(const int* __restrict__ tokens,
                             const float* __restrict__ Emb,
                             const unsigned short* __restrict__ Wx_swz,
                             const float* __restrict__ b_r, const float* __restrict__ b_z,
                             const float* __restrict__ b_c,
                             unsigned short* __restrict__ Xp) {
  __shared__ unsigned short xl[B_SZ * E_DIM];   // 64 KB
  const int s = blockIdx.y;
  const int slab = blockIdx.x;                  // 0..47
  const int tid = threadIdx.x;
  for (int it = 0; it < 32; ++it) {
    int task = tid + 256 * it;
    int row = task >> 7;
    int f = task & 127;
    int tok = tokens[row * S_LEN + s];
    float4 v = *(const float4*)(Emb + (long)tok * E_DIM + f * 4);
    int sw = (f >> 1) ^ (row & 7);
    unsigned short* p = xl + row * E_DIM + sw * 8 + (f & 1) * 4;
    p[0] = f2bf(v.x); p[1] = f2bf(v.y); p[2] = f2bf(v.z); p[3] = f2bf(v.w);
  }
  __syncthreads();
  const int lane = tid & 63, wave = tid >> 6;
  const int n = lane & 15, q = lane >> 4;
  const int jt_glob = slab * 4 + wave;
  f32x4 acc[4];
  #pragma unroll
  for (int bt = 0; bt < 4; ++bt) { acc[bt][0]=0.f; acc[bt][1]=0.f; acc[bt][2]=0.f; acc[bt][3]=0.f; }
  for (int kt = 0; kt < 16; ++kt) {
    bf16x8 bfrag = *(const bf16x8*)(Wx_swz + ((long)(jt_glob * 16 + kt) * 64 + lane) * 8);
    #pragma unroll
    for (int bt = 0; bt < 4; ++bt) {
      int row = bt * 16 + n;
      int chunk = (kt * 4 + q) ^ (row & 7);
      bf16x8 afrag = *(const bf16x8*)(xl + row * E_DIM + chunk * 8);
      acc[bt] = mfma16(afrag, bfrag, acc[bt]);
    }
  }
  const int jglob = jt_glob * 16 + n;
  const int gate = jglob >> 10, jj = jglob & 1023;
  const float bias = (gate == 0 ? b_r : gate == 1 ? b_z : b_c)[jj];
  #pragma unroll
  for (int bt = 0; bt < 4; ++bt) {              // bt == batch group
    unsigned int lo = (unsigned)f2bf(acc[bt][0] + bias) | ((unsigned)f2bf(acc[bt][1] + bias) << 16);
    unsigned int hi = (unsigned)f2bf(acc[bt][2] + bias) | ((unsigned)f2bf(acc[bt][3] + bias) << 16);
    uint2 pk; pk.x = lo; pk.y = hi;             // rows 4q..4q+3 within group
    *(uint2*)(Xp + (((long)s * 4 + bt) * NGATE + jglob) * 16 + q * 4) = pk;
  }
}

// ============================================================================
// persistent GRU (R10): R8 flag protocol + de-conflicted produce path.
//   - red[] XOR-swizzled: produce scalar reads 4-way -> 2-way (free)
//   - hmaster -> 2 registers/lane (produce maps for rh and H identical)
//   - zbuf stride 33 (kills 4-way write conflict)
//   - z-MFMA moved between rh-payload store and vmcnt(0): drain overlaps it
// Everything else identical to R8 (proven 2763 us).
// ============================================================================
__launch_bounds__(256, 1)
__global__ void gru_kernel(const unsigned short* __restrict__ Xp,
                           const unsigned short* __restrict__ Wr_swz,
                           const unsigned short* __restrict__ Wz_swz,
                           const unsigned short* __restrict__ Wc_swz,
                           unsigned short* __restrict__ Hb2,    // [2][4][32][16][32] bf16
                           float* __restrict__ Hf,              // [64][1024] f32 (last step)
                           unsigned short* __restrict__ rh2,    // [4][32][16][32] bf16
                           unsigned int* __restrict__ slots) {  // [4][32][4] padded x64
  __shared__ float red[4][6][256];              // 24 KB [src wave][slot][...]
  __shared__ float zbuf[16 * 33];               // 2.1 KB padded [row][col]

  const int tid = threadIdx.x;
  const int lane = tid & 63, w = tid >> 6;
  const int n = lane & 15, q = lane >> 4;
  const int blk = blockIdx.x;                   // 0..127
  const int g  = blk & 3;                       // batch group (rows 16g..16g+15)
  const int bh = blk >> 2;                      // j-slice [32bh, 32bh+32), bh 0..31

  // produce mapping: wave w -> rows [4w,4w+4); lane -> (row 4w+rr, cols pc,pc+1)
  const int rr = lane >> 4;                     // 0..3
  const int m  = lane & 15;
  const int prow = 4 * w + rr;                  // 0..15
  const int pc = 2 * m;                         // 0..30 (even)
  const int t0 = pc >> 4;                       // tile (same for pc, pc+1)
  const int n0 = pc & 15;

  // swizzled LDS indices (precomputed)
  const int sidx  = swz(lane * 4);                           // vector slot
  const int pidx0 = swz((w * 16 + n0) * 4 + rr);             // produce read, col pc
  const int pidx1 = swz((w * 16 + n0 + 1) * 4 + rr);         // produce read, col pc+1

  // ---- weights -> registers: per-wave K-quarter (kt = w*8..w*8+7), 2 j-tiles ----
  bf16x8 wr_reg[2][8], wz_reg[2][8], wc_reg[2][8];
  #pragma unroll
  for (int jt = 0; jt < 2; ++jt)
    #pragma unroll
    for (int t = 0; t < 8; ++t) {
      long o = ((long)((2 * bh + jt) * 32 + w * 8 + t)) * 512 + lane * 8;
      wr_reg[jt][t] = *(const bf16x8*)(Wr_swz + o);
      wz_reg[jt][t] = *(const bf16x8*)(Wz_swz + o);
      wc_reg[jt][t] = *(const bf16x8*)(Wc_swz + o);
    }

  // per-lane H state in REGISTERS (produce-rh and produce-H share the map)
  float h0r = 0.f, h1r = 0.f;                   // H0 = 0

  unsigned int* gslots = slots + g * 128 * SLOT_STRIDE;    // 32 blocks x 4 waves
  unsigned int* myflag = gslots + (bh * 4 + w) * SLOT_STRIDE;
  const unsigned int* pollp =
      gslots + ((w * 8 + (lane >> 2)) * 4 + (lane & 3)) * SLOT_STRIDE;  // lane<32

  // Xp addresses (layout: [s][g][jglob][row0..15])
  const long xp_step = (long)4 * NGATE * 16;    // shorts per step
  const unsigned short* xr_p = Xp + ((long)g * NGATE + bh * 32 + pc) * 16 + prow;
  const unsigned short* xc_p = Xp + ((long)g * NGATE + 2 * HD + bh * 32 + pc) * 16 + prow;
  const unsigned short* xz_p = Xp + ((long)g * NGATE + HD + bh * 32 + (w & 1) * 16 + n) * 16 + q * 4;

  unsigned short xr0 = xr_p[0],  xr1 = xr_p[16];
  unsigned short xc0 = xc_p[0],  xc1 = xc_p[16];
  uint2 xz; xz.x = 0; xz.y = 0;
  if (w >= 2) xz = *(const uint2*)xz_p;

  // producer store offset (u32 units): chunk (g,bh), row prow, cols pc..pc+1
  const long my32 = (long)(g * 32 + bh) * 256 + (long)prow * 16 + m;
  // consumer per-lane offset within a chunk (u64 units): row n, cols q*8..q*8+8
  const long ld64 = (long)n * 8 + q * 2;
  const long grp64 = (long)g * 4096;            // group base in u64 units

  unsigned int* rh_u32 = (unsigned int*)rh2;
  unsigned int* hb_u32 = (unsigned int*)Hb2;

  // H chunk data in regs; H0 = 0
  unsigned long long a0[8], a1[8];
  #pragma unroll
  for (int t = 0; t < 8; ++t) { a0[t] = 0ull; a1[t] = 0ull; }

  int cur = 0;
  unsigned int seq = 1;

  for (int s = 0; s < S_LEN; ++s) {
    // ============ phase A: r-MFMA ============
    f32x4 aR0, aR1;
    aR0[0]=0.f;aR0[1]=0.f;aR0[2]=0.f;aR0[3]=0.f; aR1 = aR0;
    #pragma unroll
    for (int t = 0; t < 8; ++t) {
      union { unsigned long long u[2]; bf16x8 v; } af;
      af.u[0] = a0[t]; af.u[1] = a1[t];
      aR0 = mfma16(af.v, wr_reg[0][t], aR0);
      aR1 = mfma16(af.v, wr_reg[1][t], aR1);
    }
    *(f32x4*)&red[w][0][sidx] = aR0;
    *(f32x4*)&red[w][1][sidx] = aR1;
    __syncthreads();                              // bar1
    // ---- 4-wave produce rh: lane -> (prow, pc), (prow, pc+1) ----
    {
      float v0 = 0.f, v1 = 0.f;
      #pragma unroll
      for (int k = 0; k < 4; ++k) {
        v0 += red[k][t0][pidx0];
        v1 += red[k][t0][pidx1];
      }
      float r0 = sigmoid_fast(v0 + bf2f(xr0)) * h0r;
      float r1 = sigmoid_fast(v1 + bf2f(xr1)) * h1r;
      unsigned int pay = (unsigned)f2bf(r0) | ((unsigned)f2bf(r1) << 16);
      st_u32_agent(rh_u32 + my32, pay);           // payload store issued...
    }
    // ---- z-MFMA overlaps the payload-store drain (regs + LDS only) ----
    f32x4 aZ0, aZ1;
    aZ0[0]=0.f;aZ0[1]=0.f;aZ0[2]=0.f;aZ0[3]=0.f; aZ1 = aZ0;
    #pragma unroll
    for (int t = 0; t < 8; ++t) {
      union { unsigned long long u[2]; bf16x8 v; } af;
      af.u[0] = a0[t]; af.u[1] = a1[t];
      aZ0 = mfma16(af.v, wz_reg[0][t], aZ0);
      aZ1 = mfma16(af.v, wz_reg[1][t], aZ1);
    }
    *(f32x4*)&red[w][2][sidx] = aZ0;
    *(f32x4*)&red[w][3][sidx] = aZ1;
    asm volatile("s_waitcnt vmcnt(0)" ::: "memory");   // ...drained here
    if (lane == 0) st_u32_agent(myflag, seq);
    // ---- per-wave poll of 32 producer-wave flags, then rh loads ----
    if (lane < 32) { while (ld_u32_agent(pollp) < seq) {} }
    asm volatile("" ::: "memory");
    unsigned long long rA[8], rB[8];
    #pragma unroll
    for (int t = 0; t < 8; ++t) {
      const unsigned long long* p =
          (const unsigned long long*)rh2 + grp64 + (long)(w * 8 + t) * 128 + ld64;
      rA[t] = ld_u64_agent(p);
      rB[t] = ld_u64_agent(p + 1);
    }
    __syncthreads();                              // bar2 (z partials visible)
    if (w >= 2) {                                 // z-reduce, tile tz = w-2
      const int tz = w - 2;
      f32x4 accz = *(const f32x4*)&red[0][2 + tz][sidx];
      #pragma unroll
      for (int k = 1; k < 4; ++k) { f32x4 p = *(const f32x4*)&red[k][2 + tz][sidx]; accz += p; }
      #pragma unroll
      for (int r_ = 0; r_ < 4; ++r_) {
        float xpv = bf2f((unsigned short)(((r_ < 2) ? xz.x : xz.y) >> ((r_ & 1) * 16)));
        zbuf[(q * 4 + r_) * 33 + tz * 16 + n] = sigmoid_fast(accz[r_] + xpv);
      }
    }
    // ============ phase B: c-MFMA ============
    f32x4 cA, cB;
    cA[0]=0.f;cA[1]=0.f;cA[2]=0.f;cA[3]=0.f; cB = cA;
    #pragma unroll
    for (int t = 0; t < 8; ++t) {
      union { unsigned long long u[2]; bf16x8 v; } af;
      af.u[0] = rA[t]; af.u[1] = rB[t];
      cA = mfma16(af.v, wc_reg[0][t], cA);
      cB = mfma16(af.v, wc_reg[1][t], cB);
    }
    *(f32x4*)&red[w][4][sidx] = cA;
    *(f32x4*)&red[w][5][sidx] = cB;
    __syncthreads();                              // bar3
    // ---- 4-wave produce H ----
    {
      float v0 = 0.f, v1 = 0.f;
      #pragma unroll
      for (int k = 0; k < 4; ++k) {
        v0 += red[k][4 + t0][pidx0];
        v1 += red[k][4 + t0][pidx1];
      }
      float cv0 = tanh_fast(v0 + bf2f(xc0));
      float cv1 = tanh_fast(v1 + bf2f(xc1));
      float z0 = zbuf[prow * 33 + pc], z1 = zbuf[prow * 33 + pc + 1];
      float hn0 = z0 * h0r + (1.0f - z0) * cv0;
      float hn1 = z1 * h1r + (1.0f - z1) * cv1;
      h0r = hn0; h1r = hn1;
      if (s == S_LEN - 1) {
        Hf[(long)(g * 16 + prow) * HD + bh * 32 + pc]     = hn0;
        Hf[(long)(g * 16 + prow) * HD + bh * 32 + pc + 1] = hn1;
      }
      unsigned int pay = (unsigned)f2bf(hn0) | ((unsigned)f2bf(hn1) << 16);
      st_u32_agent(hb_u32 + (long)(cur ^ 1) * 32768 + my32, pay);
      asm volatile("s_waitcnt vmcnt(0)" ::: "memory");   // own payload at LLC
      if (lane == 0) st_u32_agent(myflag, seq + 1);
    }
    // ============ free-running tail: prefetch + poll + H loads ============
    if (s < S_LEN - 1) {
      const unsigned short* xr_s = xr_p + (long)(s + 1) * xp_step;
      const unsigned short* xc_s = xc_p + (long)(s + 1) * xp_step;
      unsigned short xr0n = xr_s[0], xr1n = xr_s[16];
      unsigned short xc0n = xc_s[0], xc1n = xc_s[16];
      uint2 xzn; xzn.x = 0; xzn.y = 0;
      if (w >= 2) xzn = *(const uint2*)(xz_p + (long)(s + 1) * xp_step);
      if (lane < 32) { while (ld_u32_agent(pollp) < seq + 1) {} }
      asm volatile("" ::: "memory");
      const unsigned long long* hb =
          (const unsigned long long*)Hb2 + (long)(cur ^ 1) * 16384 + grp64;
      #pragma unroll
      for (int t = 0; t < 8; ++t) {
        const unsigned long long* p = hb + (long)(w * 8 + t) * 128 + ld64;
        a0[t] = ld_u64_agent(p);
        a1[t] = ld_u64_agent(p + 1);
      }
      xr0 = xr0n; xr1 = xr1n; xc0 = xc0n; xc1 = xc1n; xz = xzn;
    }
    seq += 2;
    cur ^= 1;
  }
}

// ============================================================================
// logits + softmax: one wave per batch row
// ============================================================================
__global__ void logits_kernel(const float* __restrict__ Hf, const float* __restrict__ Whq,
                              const float* __restrict__ bq, float* __restrict__ out) {
  const int b = blockIdx.x;
  const int lane = threadIdx.x;   // 64
  float acc[O_DIM];
  #pragma unroll
  for (int o = 0; o < O_DIM; ++o) acc[o] = 0.f;
  for (int k = lane; k < HD; k += 64) {
    float h = Hf[(long)b * HD + k];
    #pragma unroll
    for (int o = 0; o < O_DIM; ++o) acc[o] += h * Whq[(long)k * O_DIM + o];
  }
  #pragma unroll
  for (int o = 0; o < O_DIM; ++o) {
    #pragma unroll
    for (int off = 32; off > 0; off >>= 1) acc[o] += __shfl_down(acc[o], off, 64);
  }
  if (lane == 0) {
    float lg[O_DIM], m = -1e30f, sum = 0.f;
    #pragma unroll
    for (int o = 0; o < O_DIM; ++o) { lg[o] = acc[o] + bq[o]; m = fmaxf(m, lg[o]); }
    #pragma unroll
    for (int o = 0; o < O_DIM; ++o) { lg[o] = __expf(lg[o] - m); sum += lg[o]; }
    float inv = 1.0f / sum;
    #pragma unroll
    for (int o = 0; o < O_DIM; ++o) out[(long)b * O_DIM + o] = lg[o] * inv;
  }
}

// ============================================================================
extern "C" void kernel_launch(void* const* d_in, const int* in_sizes, int n_in,
                              void* d_out, int out_size, void* d_ws, size_t ws_size,
                              hipStream_t stream) {
  const int*   tokens = (const int*)d_in[0];
  const float* Emb = (const float*)d_in[1];
  const float* Wxr = (const float*)d_in[2];
  const float* Whr = (const float*)d_in[3];
  const float* br  = (const float*)d_in[4];
  const float* Wxz = (const float*)d_in[5];
  const float* Whz = (const float*)d_in[6];
  const float* bz  = (const float*)d_in[7];
  const float* Wxc = (const float*)d_in[8];
  const float* Whc = (const float*)d_in[9];
  const float* bc  = (const float*)d_in[10];
  const float* Whq = (const float*)d_in[11];
  const float* bq  = (const float*)d_in[12];

  char* ws = (char*)d_ws;
  unsigned short* Hb2    = (unsigned short*)(ws + OFF_HB2);
  unsigned short* rh2    = (unsigned short*)(ws + OFF_RH2);
  float*          Hf     = (float*)(ws + OFF_HF);
  unsigned int*   slots  = (unsigned int*)(ws + OFF_SLOTS);
  unsigned short* Wr_swz = (unsigned short*)(ws + OFF_WR);
  unsigned short* Wz_swz = (unsigned short*)(ws + OFF_WZ);
  unsigned short* Wc_swz = (unsigned short*)(ws + OFF_WC);
  unsigned short* Wx_swz = (unsigned short*)(ws + OFF_WX);
  unsigned short* Xp     = (unsigned short*)(ws + OFF_XP);

  // only the flags need zeroing (H0 in-register; buffers write-before-read)
  hipMemsetAsync(ws + OFF_SLOTS, 0, 131072, stream);

  convert_kernel<<<18432, 256, 0, stream>>>(Whr, Whz, Whc, Wxr, Wxz, Wxc,
                                            Wr_swz, Wz_swz, Wc_swz, Wx_swz);
  embed_kernel<<<dim3(48, S_LEN), 256, 0, stream>>>(tokens, Emb, Wx_swz, br, bz, bc, Xp);
  gru_kernel<<<128, 256, 0, stream>>>(Xp, Wr_swz, Wz_swz, Wc_swz,
                                      Hb2, Hf, rh2, slots);
  logits_kernel<<<B_SZ, 64, 0, stream>>>(Hf, Whq, bq, (float*)d_out);
}

// Round 8
// 3243.765 us; speedup vs baseline: 2.1520x; 1.0512x over previous
//
#include <hip/hip_runtime.h>
#include <stdint.h>

// ---------------- problem constants ----------------
#define S_LEN 512
#define B_SZ  64
#define E_DIM 512
#define HD    1024
#define NGATE 3072   // 3*HD (r,z,c)
#define O_DIM 10

typedef __attribute__((ext_vector_type(4))) float f32x4;
typedef __attribute__((ext_vector_type(8))) short bf16x8;   // 8 bf16 in 4 VGPRs

__device__ __forceinline__ float bf2f(unsigned short u) {
  union { unsigned int i; float f; } c; c.i = ((unsigned int)u) << 16; return c.f;
}
__device__ __forceinline__ unsigned short f2bf(float f) {   // RNE
  union { float f; unsigned int i; } c; c.f = f;
  unsigned int u = c.i;
  return (unsigned short)((u + 0x7fffu + ((u >> 16) & 1u)) >> 16);
}
__device__ __forceinline__ float sigmoid_fast(float x) { return 1.0f / (1.0f + __expf(-x)); }
__device__ __forceinline__ float tanh_fast(float x) {
  float a = fabsf(x);
  float e = __expf(2.0f * a);
  return copysignf(1.0f - 2.0f / (e + 1.0f), x);
}
__device__ __forceinline__ f32x4 mfma16(bf16x8 a, bf16x8 b, f32x4 c) {
  return __builtin_amdgcn_mfma_f32_16x16x32_bf16(a, b, c, 0, 0, 0);
}
// ---- device-coherent primitives (relaxed agent scope, R6/R8-proven) ----
__device__ __forceinline__ unsigned long long ld_u64_agent(const unsigned long long* p) {
  return __hip_atomic_load(p, __ATOMIC_RELAXED, __HIP_MEMORY_SCOPE_AGENT);
}
__device__ __forceinline__ unsigned int ld_u32_agent(const unsigned int* p) {
  return __hip_atomic_load(p, __ATOMIC_RELAXED, __HIP_MEMORY_SCOPE_AGENT);
}
__device__ __forceinline__ void st_u32_agent(unsigned int* p, unsigned int v) {
  __hip_atomic_store(p, v, __ATOMIC_RELAXED, __HIP_MEMORY_SCOPE_AGENT);
}

// red[] index swizzle: XOR bits5-7 into bits2-4 (bijective, keeps f32x4
// accesses 16B-contiguous). Produce-path scalar reads 4-way -> 2-way.
__device__ __forceinline__ int swz(int i) { return i ^ (((i >> 5) & 7) << 2); }

// ---------------- ws layout (bytes) ----------------
// R11 == R8 protocol & event ORDER (store -> drain -> flag FIRST, z-MFMA
// after; R10's flag-after-zMFMA cost +0.25us/step) + R10's good parts
// (reg-hmaster, swz, zbuf padding).  Payload chunks: [16 rows][32 cols] bf16.
#define SLOT_STRIDE 64       // u32s per flag slot = 256 B
#define OFF_HB2   0          // bf16 Hb2[2][4][32][16][32] = 256 KB
#define OFF_RH2   262144     // bf16 rh2[4][32][16][32]   = 128 KB
#define OFF_HF    393216     // f32 Hf[64][1024]          = 256 KB
#define OFF_SLOTS 655360     // u32 [4][32][4] x 256 B    = 128 KB
#define OFF_WR    1704960
#define OFF_WZ    3802112
#define OFF_WC    5899264
#define OFF_WX    7996416
#define OFF_XP    11142144

// ============================================================================
// convert: fp32 weights -> bf16, pre-swizzled into MFMA B-fragment order.
// ============================================================================
__global__ void convert_kernel(const float* __restrict__ Whr, const float* __restrict__ Whz,
                               const float* __restrict__ Whc,
                               const float* __restrict__ Wxr, const float* __restrict__ Wxz,
                               const float* __restrict__ Wxc,
                               unsigned short* __restrict__ Wr_swz, unsigned short* __restrict__ Wz_swz,
                               unsigned short* __restrict__ Wc_swz, unsigned short* __restrict__ Wx_swz) {
  long idx = (long)blockIdx.x * blockDim.x + threadIdx.x;
  const long NH = (long)HD * HD;
  if (idx < 3 * NH) {
    int m = (int)(idx >> 20);
    int t = (int)(idx & (NH - 1));
    int k = t >> 10, j = t & 1023;
    const float* src = (m == 0) ? Whr : (m == 1) ? Whz : Whc;
    unsigned short* dst = (m == 0) ? Wr_swz : (m == 1) ? Wz_swz : Wc_swz;
    int jt = j >> 4, n = j & 15, kt = k >> 5, q = (k >> 3) & 3, i = k & 7;
    dst[((long)(jt * 32 + kt) * 64 + (q * 16 + n)) * 8 + i] = f2bf(src[(long)k * HD + j]);
  } else {
    long t = idx - 3 * NH;
    if (t < (long)E_DIM * NGATE) {
      int e  = (int)(t / NGATE);
      int jg = (int)(t - (long)e * NGATE);
      int jt = jg >> 4, n = jg & 15, kt = e >> 5, q = (e >> 3) & 3, i = e & 7;
      int gate = jg >> 10, jj = jg & 1023;
      const float* src = (gate == 0) ? Wxr : (gate == 1) ? Wxz : Wxc;
      Wx_swz[((long)(jt * 16 + kt) * 64 + (q * 16 + n)) * 8 + i] = f2bf(src[(long)e * HD + jj]);
    }
  }
}

// ============================================================================
// embed + X-projection -> Xp[s][g][jglob][16b] (bf16, bias folded in).
// ============================================================================
__launch_bounds__(256, 2)
__global__ void embed_kernel(const int* __restrict__ tokens,
                             const float* __restrict__ Emb,
                             const unsigned short* __restrict__ Wx_swz,
                             const float* __restrict__ b_r, const float* __restrict__ b_z,
                             const float* __restrict__ b_c,
                             unsigned short* __restrict__ Xp) {
  __shared__ unsigned short xl[B_SZ * E_DIM];   // 64 KB
  const int s = blockIdx.y;
  const int slab = blockIdx.x;                  // 0..47
  const int tid = threadIdx.x;
  for (int it = 0; it < 32; ++it) {
    int task = tid + 256 * it;
    int row = task >> 7;
    int f = task & 127;
    int tok = tokens[row * S_LEN + s];
    float4 v = *(const float4*)(Emb + (long)tok * E_DIM + f * 4);
    int sw = (f >> 1) ^ (row & 7);
    unsigned short* p = xl + row * E_DIM + sw * 8 + (f & 1) * 4;
    p[0] = f2bf(v.x); p[1] = f2bf(v.y); p[2] = f2bf(v.z); p[3] = f2bf(v.w);
  }
  __syncthreads();
  const int lane = tid & 63, wave = tid >> 6;
  const int n = lane & 15, q = lane >> 4;
  const int jt_glob = slab * 4 + wave;
  f32x4 acc[4];
  #pragma unroll
  for (int bt = 0; bt < 4; ++bt) { acc[bt][0]=0.f; acc[bt][1]=0.f; acc[bt][2]=0.f; acc[bt][3]=0.f; }
  for (int kt = 0; kt < 16; ++kt) {
    bf16x8 bfrag = *(const bf16x8*)(Wx_swz + ((long)(jt_glob * 16 + kt) * 64 + lane) * 8);
    #pragma unroll
    for (int bt = 0; bt < 4; ++bt) {
      int row = bt * 16 + n;
      int chunk = (kt * 4 + q) ^ (row & 7);
      bf16x8 afrag = *(const bf16x8*)(xl + row * E_DIM + chunk * 8);
      acc[bt] = mfma16(afrag, bfrag, acc[bt]);
    }
  }
  const int jglob = jt_glob * 16 + n;
  const int gate = jglob >> 10, jj = jglob & 1023;
  const float bias = (gate == 0 ? b_r : gate == 1 ? b_z : b_c)[jj];
  #pragma unroll
  for (int bt = 0; bt < 4; ++bt) {              // bt == batch group
    unsigned int lo = (unsigned)f2bf(acc[bt][0] + bias) | ((unsigned)f2bf(acc[bt][1] + bias) << 16);
    unsigned int hi = (unsigned)f2bf(acc[bt][2] + bias) | ((unsigned)f2bf(acc[bt][3] + bias) << 16);
    uint2 pk; pk.x = lo; pk.y = hi;             // rows 4q..4q+3 within group
    *(uint2*)(Xp + (((long)s * 4 + bt) * NGATE + jglob) * 16 + q * 4) = pk;
  }
}

// ============================================================================
// persistent GRU (R11): R8 event order + shortened produce.
//   produce: store -> vmcnt(0) -> flag IMMEDIATELY (consumer-visible event
//   as early as possible); z-MFMA after flag absorbs flag-flight/skew before
//   the poll.  hmaster in registers; red[] swizzled; zbuf padded.
// ============================================================================
__launch_bounds__(256, 1)
__global__ void gru_kernel(const unsigned short* __restrict__ Xp,
                           const unsigned short* __restrict__ Wr_swz,
                           const unsigned short* __restrict__ Wz_swz,
                           const unsigned short* __restrict__ Wc_swz,
                           unsigned short* __restrict__ Hb2,    // [2][4][32][16][32] bf16
                           float* __restrict__ Hf,              // [64][1024] f32 (last step)
                           unsigned short* __restrict__ rh2,    // [4][32][16][32] bf16
                           unsigned int* __restrict__ slots) {  // [4][32][4] padded x64
  __shared__ float red[4][6][256];              // 24 KB [src wave][slot][...]
  __shared__ float zbuf[16 * 33];               // 2.1 KB padded [row][col]

  const int tid = threadIdx.x;
  const int lane = tid & 63, w = tid >> 6;
  const int n = lane & 15, q = lane >> 4;
  const int blk = blockIdx.x;                   // 0..127
  const int g  = blk & 3;                       // batch group (rows 16g..16g+15)
  const int bh = blk >> 2;                      // j-slice [32bh, 32bh+32), bh 0..31

  // produce mapping: wave w -> rows [4w,4w+4); lane -> (row 4w+rr, cols pc,pc+1)
  const int rr = lane >> 4;                     // 0..3
  const int m  = lane & 15;
  const int prow = 4 * w + rr;                  // 0..15
  const int pc = 2 * m;                         // 0..30 (even)
  const int t0 = pc >> 4;                       // tile (same for pc, pc+1)
  const int n0 = pc & 15;

  // swizzled LDS indices (precomputed)
  const int sidx  = swz(lane * 4);                           // vector slot
  const int pidx0 = swz((w * 16 + n0) * 4 + rr);             // produce read, col pc
  const int pidx1 = swz((w * 16 + n0 + 1) * 4 + rr);         // produce read, col pc+1

  // ---- weights -> registers: per-wave K-quarter (kt = w*8..w*8+7), 2 j-tiles ----
  bf16x8 wr_reg[2][8], wz_reg[2][8], wc_reg[2][8];
  #pragma unroll
  for (int jt = 0; jt < 2; ++jt)
    #pragma unroll
    for (int t = 0; t < 8; ++t) {
      long o = ((long)((2 * bh + jt) * 32 + w * 8 + t)) * 512 + lane * 8;
      wr_reg[jt][t] = *(const bf16x8*)(Wr_swz + o);
      wz_reg[jt][t] = *(const bf16x8*)(Wz_swz + o);
      wc_reg[jt][t] = *(const bf16x8*)(Wc_swz + o);
    }

  // per-lane H state in REGISTERS (produce-rh and produce-H share the map)
  float h0r = 0.f, h1r = 0.f;                   // H0 = 0

  unsigned int* gslots = slots + g * 128 * SLOT_STRIDE;    // 32 blocks x 4 waves
  unsigned int* myflag = gslots + (bh * 4 + w) * SLOT_STRIDE;
  const unsigned int* pollp =
      gslots + ((w * 8 + (lane >> 2)) * 4 + (lane & 3)) * SLOT_STRIDE;  // lane<32

  // Xp addresses (layout: [s][g][jglob][row0..15])
  const long xp_step = (long)4 * NGATE * 16;    // shorts per step
  const unsigned short* xr_p = Xp + ((long)g * NGATE + bh * 32 + pc) * 16 + prow;
  const unsigned short* xc_p = Xp + ((long)g * NGATE + 2 * HD + bh * 32 + pc) * 16 + prow;
  const unsigned short* xz_p = Xp + ((long)g * NGATE + HD + bh * 32 + (w & 1) * 16 + n) * 16 + q * 4;

  unsigned short xr0 = xr_p[0],  xr1 = xr_p[16];
  unsigned short xc0 = xc_p[0],  xc1 = xc_p[16];
  uint2 xz; xz.x = 0; xz.y = 0;
  if (w >= 2) xz = *(const uint2*)xz_p;

  // producer store offset (u32 units): chunk (g,bh), row prow, cols pc..pc+1
  const long my32 = (long)(g * 32 + bh) * 256 + (long)prow * 16 + m;
  // consumer per-lane offset within a chunk (u64 units): row n, cols q*8..q*8+8
  const long ld64 = (long)n * 8 + q * 2;
  const long grp64 = (long)g * 4096;            // group base in u64 units

  unsigned int* rh_u32 = (unsigned int*)rh2;
  unsigned int* hb_u32 = (unsigned int*)Hb2;

  // H chunk data in regs; H0 = 0
  unsigned long long a0[8], a1[8];
  #pragma unroll
  for (int t = 0; t < 8; ++t) { a0[t] = 0ull; a1[t] = 0ull; }

  int cur = 0;
  unsigned int seq = 1;

  for (int s = 0; s < S_LEN; ++s) {
    // ============ phase A: r-MFMA ============
    f32x4 aR0, aR1;
    aR0[0]=0.f;aR0[1]=0.f;aR0[2]=0.f;aR0[3]=0.f; aR1 = aR0;
    #pragma unroll
    for (int t = 0; t < 8; ++t) {
      union { unsigned long long u[2]; bf16x8 v; } af;
      af.u[0] = a0[t]; af.u[1] = a1[t];
      aR0 = mfma16(af.v, wr_reg[0][t], aR0);
      aR1 = mfma16(af.v, wr_reg[1][t], aR1);
    }
    *(f32x4*)&red[w][0][sidx] = aR0;
    *(f32x4*)&red[w][1][sidx] = aR1;
    __syncthreads();                              // bar1
    // ---- 4-wave produce rh: store -> drain -> flag, immediately ----
    {
      float v0 = 0.f, v1 = 0.f;
      #pragma unroll
      for (int k = 0; k < 4; ++k) {
        v0 += red[k][t0][pidx0];
        v1 += red[k][t0][pidx1];
      }
      float r0 = sigmoid_fast(v0 + bf2f(xr0)) * h0r;
      float r1 = sigmoid_fast(v1 + bf2f(xr1)) * h1r;
      unsigned int pay = (unsigned)f2bf(r0) | ((unsigned)f2bf(r1) << 16);
      st_u32_agent(rh_u32 + my32, pay);
      asm volatile("s_waitcnt vmcnt(0)" ::: "memory");   // payload at LLC
      if (lane == 0) st_u32_agent(myflag, seq);          // flag ASAP
    }
    // ---- z-MFMA after flag: absorbs flag-flight/skew before the poll ----
    f32x4 aZ0, aZ1;
    aZ0[0]=0.f;aZ0[1]=0.f;aZ0[2]=0.f;aZ0[3]=0.f; aZ1 = aZ0;
    #pragma unroll
    for (int t = 0; t < 8; ++t) {
      union { unsigned long long u[2]; bf16x8 v; } af;
      af.u[0] = a0[t]; af.u[1] = a1[t];
      aZ0 = mfma16(af.v, wz_reg[0][t], aZ0);
      aZ1 = mfma16(af.v, wz_reg[1][t], aZ1);
    }
    *(f32x4*)&red[w][2][sidx] = aZ0;
    *(f32x4*)&red[w][3][sidx] = aZ1;
    // ---- per-wave poll of 32 producer-wave flags, then rh loads ----
    if (lane < 32) { while (ld_u32_agent(pollp) < seq) {} }
    asm volatile("" ::: "memory");
    unsigned long long rA[8], rB[8];
    #pragma unroll
    for (int t = 0; t < 8; ++t) {
      const unsigned long long* p =
          (const unsigned long long*)rh2 + grp64 + (long)(w * 8 + t) * 128 + ld64;
      rA[t] = ld_u64_agent(p);
      rB[t] = ld_u64_agent(p + 1);
    }
    __syncthreads();                              // bar2 (z partials visible)
    if (w >= 2) {                                 // z-reduce, tile tz = w-2
      const int tz = w - 2;
      f32x4 accz = *(const f32x4*)&red[0][2 + tz][sidx];
      #pragma unroll
      for (int k = 1; k < 4; ++k) { f32x4 p = *(const f32x4*)&red[k][2 + tz][sidx]; accz += p; }
      #pragma unroll
      for (int r_ = 0; r_ < 4; ++r_) {
        float xpv = bf2f((unsigned short)(((r_ < 2) ? xz.x : xz.y) >> ((r_ & 1) * 16)));
        zbuf[(q * 4 + r_) * 33 + tz * 16 + n] = sigmoid_fast(accz[r_] + xpv);
      }
    }
    // ============ phase B: c-MFMA ============
    f32x4 cA, cB;
    cA[0]=0.f;cA[1]=0.f;cA[2]=0.f;cA[3]=0.f; cB = cA;
    #pragma unroll
    for (int t = 0; t < 8; ++t) {
      union { unsigned long long u[2]; bf16x8 v; } af;
      af.u[0] = rA[t]; af.u[1] = rB[t];
      cA = mfma16(af.v, wc_reg[0][t], cA);
      cB = mfma16(af.v, wc_reg[1][t], cB);
    }
    *(f32x4*)&red[w][4][sidx] = cA;
    *(f32x4*)&red[w][5][sidx] = cB;
    __syncthreads();                              // bar3
    // ---- 4-wave produce H: store -> drain -> flag ----
    {
      float v0 = 0.f, v1 = 0.f;
      #pragma unroll
      for (int k = 0; k < 4; ++k) {
        v0 += red[k][4 + t0][pidx0];
        v1 += red[k][4 + t0][pidx1];
      }
      float cv0 = tanh_fast(v0 + bf2f(xc0));
      float cv1 = tanh_fast(v1 + bf2f(xc1));
      float z0 = zbuf[prow * 33 + pc], z1 = zbuf[prow * 33 + pc + 1];
      float hn0 = z0 * h0r + (1.0f - z0) * cv0;
      float hn1 = z1 * h1r + (1.0f - z1) * cv1;
      h0r = hn0; h1r = hn1;
      if (s == S_LEN - 1) {
        Hf[(long)(g * 16 + prow) * HD + bh * 32 + pc]     = hn0;
        Hf[(long)(g * 16 + prow) * HD + bh * 32 + pc + 1] = hn1;
      }
      unsigned int pay = (unsigned)f2bf(hn0) | ((unsigned)f2bf(hn1) << 16);
      st_u32_agent(hb_u32 + (long)(cur ^ 1) * 32768 + my32, pay);
      asm volatile("s_waitcnt vmcnt(0)" ::: "memory");   // payload at LLC
      if (lane == 0) st_u32_agent(myflag, seq + 1);
    }
    // ============ free-running tail: prefetch + poll + H loads ============
    if (s < S_LEN - 1) {
      const unsigned short* xr_s = xr_p + (long)(s + 1) * xp_step;
      const unsigned short* xc_s = xc_p + (long)(s + 1) * xp_step;
      unsigned short xr0n = xr_s[0], xr1n = xr_s[16];
      unsigned short xc0n = xc_s[0], xc1n = xc_s[16];
      uint2 xzn; xzn.x = 0; xzn.y = 0;
      if (w >= 2) xzn = *(const uint2*)(xz_p + (long)(s + 1) * xp_step);
      if (lane < 32) { while (ld_u32_agent(pollp) < seq + 1) {} }
      asm volatile("" ::: "memory");
      const unsigned long long* hb =
          (const unsigned long long*)Hb2 + (long)(cur ^ 1) * 16384 + grp64;
      #pragma unroll
      for (int t = 0; t < 8; ++t) {
        const unsigned long long* p = hb + (long)(w * 8 + t) * 128 + ld64;
        a0[t] = ld_u64_agent(p);
        a1[t] = ld_u64_agent(p + 1);
      }
      xr0 = xr0n; xr1 = xr1n; xc0 = xc0n; xc1 = xc1n; xz = xzn;
    }
    seq += 2;
    cur ^= 1;
  }
}

// ============================================================================
// logits + softmax: one wave per batch row
// ============================================================================
__global__ void logits_kernel(const float* __restrict__ Hf, const float* __restrict__ Whq,
                              const float* __restrict__ bq, float* __restrict__ out) {
  const int b = blockIdx.x;
  const int lane = threadIdx.x;   // 64
  float acc[O_DIM];
  #pragma unroll
  for (int o = 0; o < O_DIM; ++o) acc[o] = 0.f;
  for (int k = lane; k < HD; k += 64) {
    float h = Hf[(long)b * HD + k];
    #pragma unroll
    for (int o = 0; o < O_DIM; ++o) acc[o] += h * Whq[(long)k * O_DIM + o];
  }
  #pragma unroll
  for (int o = 0; o < O_DIM; ++o) {
    #pragma unroll
    for (int off = 32; off > 0; off >>= 1) acc[o] += __shfl_down(acc[o], off, 64);
  }
  if (lane == 0) {
    float lg[O_DIM], m = -1e30f, sum = 0.f;
    #pragma unroll
    for (int o = 0; o < O_DIM; ++o) { lg[o] = acc[o] + bq[o]; m = fmaxf(m, lg[o]); }
    #pragma unroll
    for (int o = 0; o < O_DIM; ++o) { lg[o] = __expf(lg[o] - m); sum += lg[o]; }
    float inv = 1.0f / sum;
    #pragma unroll
    for (int o = 0; o < O_DIM; ++o) out[(long)b * O_DIM + o] = lg[o] * inv;
  }
}

// ============================================================================
extern "C" void kernel_launch(void* const* d_in, const int* in_sizes, int n_in,
                              void* d_out, int out_size, void* d_ws, size_t ws_size,
                              hipStream_t stream) {
  const int*   tokens = (const int*)d_in[0];
  const float* Emb = (const float*)d_in[1];
  const float* Wxr = (const float*)d_in[2];
  const float* Whr = (const float*)d_in[3];
  const float* br  = (const float*)d_in[4];
  const float* Wxz = (const float*)d_in[5];
  const float* Whz = (const float*)d_in[6];
  const float* bz  = (const float*)d_in[7];
  const float* Wxc = (const float*)d_in[8];
  const float* Whc = (const float*)d_in[9];
  const float* bc  = (const float*)d_in[10];
  const float* Whq = (const float*)d_in[11];
  const float* bq  = (const float*)d_in[12];

  char* ws = (char*)d_ws;
  unsigned short* Hb2    = (unsigned short*)(ws + OFF_HB2);
  unsigned short* rh2    = (unsigned short*)(ws + OFF_RH2);
  float*          Hf     = (float*)(ws + OFF_HF);
  unsigned int*   slots  = (unsigned int*)(ws + OFF_SLOTS);
  unsigned short* Wr_swz = (unsigned short*)(ws + OFF_WR);
  unsigned short* Wz_swz = (unsigned short*)(ws + OFF_WZ);
  unsigned short* Wc_swz = (unsigned short*)(ws + OFF_WC);
  unsigned short* Wx_swz = (unsigned short*)(ws + OFF_WX);
  unsigned short* Xp     = (unsigned short*)(ws + OFF_XP);

  // only the flags need zeroing (H0 in-register; buffers write-before-read)
  hipMemsetAsync(ws + OFF_SLOTS, 0, 131072, stream);

  convert_kernel<<<18432, 256, 0, stream>>>(Whr, Whz, Whc, Wxr, Wxz, Wxc,
                                            Wr_swz, Wz_swz, Wc_swz, Wx_swz);
  embed_kernel<<<dim3(48, S_LEN), 256, 0, stream>>>(tokens, Emb, Wx_swz, br, bz, bc, Xp);
  gru_kernel<<<128, 256, 0, stream>>>(Xp, Wr_swz, Wz_swz, Wc_swz,
                                      Hb2, Hf, rh2, slots);
  logits_kernel<<<B_SZ, 64, 0, stream>>>(Hf, Whq, bq, (float*)d_out);
}